// Round 1
// baseline (371.479 us; speedup 1.0000x reference)
//
#include <hip/hip_runtime.h>
#include <math.h>

#define CONF 0.25f
#define NCLS 80

// ---------------------------------------------------------------------------
// init: first_fail sentinel = k (rows with score<CONF atomicMin into it)
// ---------------------------------------------------------------------------
__global__ void init_kernel(unsigned int* __restrict__ first_fail, unsigned int k) {
    *first_fail = k;
}

// ---------------------------------------------------------------------------
// score pass: 4 lanes per row. Lanes 0..3 of each group read the row's
// 80 floats as 20 float4 (5 each, interleaved) -> contiguous 320B per row,
// full cache-line utilization. Group max via shfl_xor(1),(2).
// Lane 0 of group writes scores[row], boxsum[row], and flags score<CONF.
// ---------------------------------------------------------------------------
__global__ __launch_bounds__(256) void score_kernel(
    const float* __restrict__ logits,
    const float* __restrict__ boxes,
    float* __restrict__ scores,
    float* __restrict__ boxsum,
    unsigned int* __restrict__ first_fail,
    unsigned int k)
{
    const int tid   = threadIdx.x;
    const int lane4 = tid & 3;
    const int grp   = tid >> 2;                       // 0..63 rows per block
    const unsigned int row = blockIdx.x * 64u + (unsigned int)grp;
    if (row >= k) return;

    const float4* rp = (const float4*)(logits + (size_t)row * NCLS);
    float m = -INFINITY;
#pragma unroll
    for (int t = 0; t < 5; ++t) {
        float4 v = rp[lane4 + 4 * t];
        m = fmaxf(m, fmaxf(fmaxf(v.x, v.y), fmaxf(v.z, v.w)));
    }
    // reduce across the aligned 4-lane group
    m = fmaxf(m, __shfl_xor(m, 1));
    m = fmaxf(m, __shfl_xor(m, 2));

    if (lane4 == 0) {
        scores[row] = m;
        float4 b = ((const float4*)boxes)[row];
        boxsum[row] = (b.x + b.y) + (b.z + b.w);
        if (m < CONF) atomicMin(first_fail, row);     // rare path
    }
}

// ---------------------------------------------------------------------------
// reduce: sum scores[i]+boxsum[i] for i < j over 2MB ws arrays (L2-hot).
// Deterministic per-block reduction -> partials[blockIdx].
// ---------------------------------------------------------------------------
__global__ __launch_bounds__(256) void reduce_kernel(
    const float* __restrict__ scores,
    const float* __restrict__ boxsum,
    const unsigned int* __restrict__ first_fail,
    float* __restrict__ partials,
    unsigned int k)
{
    unsigned int j = *first_fail;
    if (j > k) j = k;

    float s = 0.0f;
    const unsigned int stride = gridDim.x * blockDim.x;
    for (unsigned int i = blockIdx.x * blockDim.x + threadIdx.x; i < j; i += stride)
        s += scores[i] + boxsum[i];

    // wave64 reduce
#pragma unroll
    for (int o = 32; o > 0; o >>= 1) s += __shfl_down(s, o);

    __shared__ float ls[4];
    const int lane = threadIdx.x & 63;
    const int wid  = threadIdx.x >> 6;
    if (lane == 0) ls[wid] = s;
    __syncthreads();
    if (threadIdx.x == 0)
        partials[blockIdx.x] = (ls[0] + ls[1]) + (ls[2] + ls[3]);
}

// ---------------------------------------------------------------------------
// final: one wave sums the 256 partials, writes the scalar.
// ---------------------------------------------------------------------------
__global__ void final_kernel(const float* __restrict__ partials, float* __restrict__ out) {
    float s = partials[threadIdx.x] + partials[threadIdx.x + 64] +
              partials[threadIdx.x + 128] + partials[threadIdx.x + 192];
#pragma unroll
    for (int o = 32; o > 0; o >>= 1) s += __shfl_down(s, o);
    if (threadIdx.x == 0) out[0] = s;
}

extern "C" void kernel_launch(void* const* d_in, const int* in_sizes, int n_in,
                              void* d_out, int out_size, void* d_ws, size_t ws_size,
                              hipStream_t stream) {
    const float* logits = (const float*)d_in[0];
    const float* boxes  = (const float*)d_in[1];
    float* out = (float*)d_out;

    const unsigned int N = (unsigned int)(in_sizes[0] / NCLS);
    unsigned int k = N / 4;                 // RATIO = 0.25, int truncation
    if (k < 1) k = 1;

    // ws layout: [0] first_fail (u32) | [256] partials (256 f32) |
    //            [4096] scores (k f32) | [4096+4k] boxsum (k f32)
    char* ws = (char*)d_ws;
    unsigned int* first_fail = (unsigned int*)ws;
    float* partials = (float*)(ws + 256);
    float* scores   = (float*)(ws + 4096);
    float* boxsum   = (float*)(ws + 4096 + (size_t)k * 4);

    init_kernel<<<1, 1, 0, stream>>>(first_fail, k);

    const unsigned int nb = (k + 63u) / 64u;
    score_kernel<<<nb, 256, 0, stream>>>(logits, boxes, scores, boxsum, first_fail, k);

    reduce_kernel<<<256, 256, 0, stream>>>(scores, boxsum, first_fail, partials, k);

    final_kernel<<<1, 64, 0, stream>>>(partials, out);
}